// Round 1
// baseline (664.192 us; speedup 1.0000x reference)
//
#include <hip/hip_runtime.h>
#include <cstdint>
#include <cstddef>

typedef unsigned int u32;
typedef unsigned long long u64;

#define NB 8
#define GH 128
#define GW 128
#define NA 9
#define NC 86
#define NANCH (GH*GW*NA)      /* 147456 */
#define BLOCKS_PER_IMG (NANCH/256)   /* 576 */
#define TOPK 1000
#define KCAP 1024
#define CANDCAP 2048
#define VALIDCAP 65536
#define HBINS 1024            /* scores>=0.5 -> key>>16 in [48896, ~49344] */
#define HBASE 48896u

/* ---- workspace layout (bytes) ---- */
#define OFF_HIST      ((size_t)0)
#define SZ_HIST       ((size_t)NB*HBINS*4)            /* 32 KB */
#define OFF_VCNT      (OFF_HIST + SZ_HIST)
#define OFF_CCNT      (OFF_VCNT + 32)
#define MEMSET_BYTES  (OFF_CCNT + 32)                 /* zero hist + counters */
#define OFF_CUT       (MEMSET_BYTES)
#define OFF_M         (OFF_CUT + 32)
#define OFF_VBUF      (OFF_M + 32)
#define SZ_VBUF       ((size_t)NB*VALIDCAP*8)
#define OFF_CBUF      (OFF_VBUF + SZ_VBUF)
#define SZ_CBUF       ((size_t)NB*CANDCAP*8)
#define OFF_DET       (OFF_CBUF + SZ_CBUF)
#define SZ_DET        ((size_t)NB*KCAP*8*4)
#define OFF_COR       (OFF_DET + SZ_DET)
#define SZ_COR        ((size_t)NB*KCAP*16)
#define OFF_AREA      (OFF_COR + SZ_COR)
#define SZ_AREA       ((size_t)NB*KCAP*4)
#define OFF_MASK      (OFF_AREA + SZ_AREA)
#define SZ_MASK       ((size_t)NB*KCAP*16*8)

__device__ __forceinline__ u64 shfl64(u64 v, int src) {
    int lo = __shfl((int)(v & 0xffffffffull), src, 64);
    int hi = __shfl((int)(v >> 32), src, 64);
    return ((u64)(u32)hi << 32) | (u32)lo;
}
__device__ __forceinline__ u64 shfl64_xor(u64 v, int m) {
    int lo = __shfl_xor((int)(v & 0xffffffffull), m, 64);
    int hi = __shfl_xor((int)(v >> 32), m, 64);
    return ((u64)(u32)hi << 32) | (u32)lo;
}
__device__ __forceinline__ u64 readlane64(u64 v, int lane) {
    int lo = __builtin_amdgcn_readlane((int)(v & 0xffffffffull), lane);
    int hi = __builtin_amdgcn_readlane((int)(v >> 32), lane);
    return ((u64)(u32)hi << 32) | (u32)lo;
}

/* 1: strided score scan -> small histogram + valid (key,~idx) compaction. */
__global__ __launch_bounds__(256) void k1_hist(const float* __restrict__ in,
                        u32* __restrict__ hist,
                        int* __restrict__ vcnt, u64* __restrict__ vbuf) {
    __shared__ int wcnt[4];
    __shared__ int woff[4];
    __shared__ int blockbase;
    int gid = blockIdx.x * 256 + threadIdx.x;
    int b = blockIdx.x / BLOCKS_PER_IMG;
    int lane = threadIdx.x & 63;
    int wv = threadIdx.x >> 6;
    float sc = in[(size_t)gid * NC + 5];
    bool valid = (sc >= 0.5f);
    u32 key = 0;
    if (valid) {
        key = __float_as_uint(sc) ^ 0x80000000u;       /* positive floats: monotone */
        u32 bin = key >> 16;
        if (bin < HBASE) bin = HBASE;                  /* can't occur; safety */
        if (bin > HBASE + HBINS - 1) bin = HBASE + HBINS - 1; /* exactness-safe */
        atomicAdd(&hist[(b << 10) + (bin - HBASE)], 1u);
    }
    u64 mask = __ballot(valid);
    if (lane == 0) wcnt[wv] = __popcll(mask);
    __syncthreads();
    if (threadIdx.x == 0) {
        int c0 = wcnt[0], c1 = wcnt[1], c2 = wcnt[2], c3 = wcnt[3];
        woff[0] = 0; woff[1] = c0; woff[2] = c0 + c1; woff[3] = c0 + c1 + c2;
        blockbase = atomicAdd(&vcnt[b], c0 + c1 + c2 + c3);
    }
    __syncthreads();
    if (valid) {
        int prefix = __popcll(mask & ((1ull << lane) - 1ull));
        int p = blockbase + woff[wv] + prefix;
        u32 n = (u32)(gid - b * NANCH);
        if (p < VALIDCAP) vbuf[((size_t)b << 16) + p] = ((u64)key << 32) | (u32)(~n);
    }
}

/* 2+3+4+5 fused, one block of 1024 threads per image:
   - cut bin via parallel suffix-scan of the 1024-bin histogram (in LDS)
   - gather candidates (bin >= cut) from vbuf straight into LDS
   - bitonic sort (descending) with wave-chunk-local phases barrier-free:
       for j <= 64, thread t=64w+s only touches elements [128w, 128w+128),
       and same-wave DS ops complete in order -> __syncthreads only for j>=64
   - decode top-M in place from sorted LDS (cbuf never materialized) */
__global__ __launch_bounds__(1024) void k2345_cut_sort_decode(
                        const float* __restrict__ in,
                        const u32* __restrict__ hist,
                        const u64* __restrict__ vbuf,
                        const int* __restrict__ vcnt,
                        int* __restrict__ Mb,
                        float* __restrict__ det,
                        float4* __restrict__ cor,
                        float* __restrict__ area) {
    __shared__ u64 buf[CANDCAP];
    __shared__ int lcnt;
    __shared__ u32 cutsh;
    int b = blockIdx.x, t = threadIdx.x;

    /* ---- cut: suffix sums of hist[b][*] (alias buf's first 4 KB as u32) ---- */
    u32* ssum = (u32*)buf;
    ssum[t] = hist[(b << 10) + t];
    if (t == 0) { lcnt = 0; cutsh = 0u; }
    __syncthreads();
    for (int off = 1; off < 1024; off <<= 1) {
        u32 add = (t + off < 1024) ? ssum[t + off] : 0u;
        __syncthreads();
        ssum[t] += add;
        __syncthreads();
    }
    /* largest bin t with suffix >= TOPK (unique); none -> cut stays 0 (take all) */
    u32 S = ssum[t];
    u32 Sn = (t < 1023) ? ssum[t + 1] : 0u;
    if (S >= (u32)TOPK && Sn < (u32)TOPK) cutsh = (u32)t + HBASE;
    __syncthreads();                  /* also fences ssum reads before buf reuse */
    u32 cutv = cutsh;

    /* ---- gather candidates into LDS ---- */
    int cnt = vcnt[b]; if (cnt > VALIDCAP) cnt = VALIDCAP;
    for (int i = t; i < cnt; i += 1024) {
        u64 comp = vbuf[((size_t)b << 16) + i];
        if ((u32)(comp >> 48) >= cutv) {
            int p = atomicAdd(&lcnt, 1);
            if (p < CANDCAP) buf[p] = comp;
        }
    }
    __syncthreads();
    int M = lcnt; if (M > CANDCAP) M = CANDCAP;
    if (t >= M) buf[t] = 0ull;
    if (t + 1024 >= M) buf[t + 1024] = 0ull;
    __syncthreads();

    /* ---- bitonic sort, descending; barriers only where phases cross chunks */
    for (int k = 2; k <= CANDCAP; k <<= 1)
        for (int j = k >> 1; j > 0; j >>= 1) {
            if (j >= 64) __syncthreads();
            int i = ((t & ~(j - 1)) << 1) | (t & (j - 1));
            int l = i | j;
            u64 a = buf[i], c = buf[l];
            bool up = ((i & k) == 0);
            if (up ? (a < c) : (a > c)) { buf[i] = c; buf[l] = a; }
        }
    __syncthreads();

    int M2 = M < TOPK ? M : TOPK;
    if (t == 0) Mb[b] = M2;

    /* ---- decode top-M2 from sorted LDS ---- */
    if (t < M2) {
        u64 comp = buf[t];
        u32 idx = ~(u32)comp;
        int a = idx % 9; int cell = idx / 9;
        int gj = cell & 127, gi = cell >> 7;
        float ci = (gi + 0.5f) * (1.0f / GH);
        float cj = (gj + 0.5f) * (1.0f / GW);
        const float SCL[3] = {0.5f, 1.0f, 2.0f};
        float s = SCL[a / 3], r = SCL[a % 3];
        float sq = sqrtf(r);
        float ah = (s * sq) * (4.0f / GH);
        float aw = (s / sq) * (4.0f / GW);
        const float* row = in + ((size_t)b * NANCH + idx) * NC;
        float t0 = row[0], t1 = row[1], t2 = row[2], t3 = row[3], scv = row[5];
        float di = ci + t0 * ah;
        float dj = cj + t1 * aw;
        float dh = ah * expf(t2);
        float dw = aw * expf(t3);
        float i0 = di - dh * 0.5f, j0 = dj - dw * 0.5f;
        float i1 = di + dh * 0.5f, j1 = dj + dw * 0.5f;
        float best = row[6]; int lab = 0;
        for (int c = 1; c < 80; ++c) { float v = row[6 + c]; if (v > best) { best = v; lab = c; } }
        float* d = det + (size_t)(b * KCAP + t) * 8;
        d[0] = di; d[1] = dj; d[2] = dh; d[3] = dw; d[4] = (float)lab; d[5] = scv;
        cor[b * KCAP + t] = make_float4(i0, j0, i1, j1);
        area[b * KCAP + t] = (i1 - i0) * (j1 - j0);
    }
}

/* 6: IoU suppression bitmask; 4 rows per block, cor/area staged in LDS */
__global__ __launch_bounds__(256) void k6_mask(const float4* __restrict__ cor,
                        const float* __restrict__ area,
                        const int* __restrict__ Mb, u64* __restrict__ mask) {
    __shared__ float4 scor[KCAP];
    __shared__ float sarea[KCAP];
    int b = blockIdx.x >> 8;                 /* 256 blocks per image */
    int i = ((blockIdx.x & 255) << 2) + (threadIdx.x >> 6);
    int lane = threadIdx.x & 63;
    int m = Mb[b];
    for (int idx = threadIdx.x; idx < KCAP; idx += 256) {
        scor[idx] = cor[b * KCAP + idx];
        sarea[idx] = area[b * KCAP + idx];
    }
    __syncthreads();
    if (i >= m) return;
    float4 bi = scor[i]; float ai = sarea[i];
    u64* rowp = mask + ((size_t)(b * KCAP + i)) * 16;
    for (int w = 0; w < 16; ++w) {
        int j = w * 64 + lane;
        bool pred = false;
        if (j > i && j < m) {
            float4 bj = scor[j]; float aj = sarea[j];
            float ti = fmaxf(bi.x, bj.x), tj = fmaxf(bi.y, bj.y);
            float b2 = fminf(bi.z, bj.z), b3 = fminf(bi.w, bj.w);
            float inter = fmaxf(b2 - ti, 0.0f) * fmaxf(b3 - tj, 0.0f);
            float uni = (ai + aj) - inter;
            float iou = inter / fmaxf(uni, 1e-12f);
            pred = iou > 0.75f;
        }
        u64 word = __ballot(pred);
        if (lane == w) rowp[w] = word;
    }
}

/* 7+8 merged: serial greedy scan (wave 0, register/readlane recurrence)
   then rank kept bits + emit 100 rows (both waves) */
__global__ __launch_bounds__(128) void k78_scan_out(const u64* __restrict__ mask,
                        const int* __restrict__ Mb, const float* __restrict__ det,
                        float* __restrict__ out) {
    __shared__ u64 kw[16];
    __shared__ int cum[17];
    int b = blockIdx.x, t = threadIdx.x;
    int m = Mb[b];
    if (t < 64) {
        int lane = t;
        const u64* mk = mask + (size_t)b * KCAP * 16;
        int myw = lane & 15;
        int myq = lane >> 4;
        u64 supp = 0;
        u64 colW = (lane < m) ? mk[(size_t)lane * 16 + 0] : 0ull;
        for (int g = 0; g < 16; ++g) {
            u64 rowW = colW;
            if (g + 1 < 16) {
                int rn = (g + 1) * 64 + lane;
                colW = (rn < m) ? mk[(size_t)rn * 16 + (g + 1)] : 0ull;
            }
            u64 cur = shfl64(supp, g);
            int lim = m - g * 64;
            u64 keptW = 0;
            #pragma unroll
            for (int s = 0; s < 64; ++s) {
                u64 w = readlane64(rowW, s);
                bool kept = (s < lim) && !((cur >> s) & 1ull);
                if (kept) { keptW |= (1ull << s); cur |= w; }
            }
            if (lane == 0) kw[g] = keptW;
            u64 acc = 0;
            #pragma unroll
            for (int s = 0; s < 16; ++s) {
                int r = myq * 16 + s;
                if ((keptW >> r) & 1ull)
                    acc |= mk[(size_t)(g * 64 + r) * 16 + myw];
            }
            acc |= shfl64_xor(acc, 16);
            acc |= shfl64_xor(acc, 32);
            if (lane < 16) supp |= acc;
        }
    }
    __syncthreads();
    if (t == 0) {
        int c = 0;
        for (int w = 0; w < 16; ++w) { cum[w] = c; c += __builtin_popcountll(kw[w]); }
        cum[16] = c;
    }
    __syncthreads();
    int total = cum[16];
    if (t < 100) {
        float o0 = 0, o1 = 0, o2 = 0, o3 = 0, o4 = 0, o5 = 0;
        if (t < total) {
            int w = 0;
            while (w < 15 && cum[w + 1] <= t) w++;
            int j = t - cum[w];
            u64 word = kw[w];
            for (int q = 0; q < j; ++q) word &= word - 1;
            int pos = __builtin_ctzll(word);
            int c = w * 64 + pos;
            const float* d = det + (size_t)(b * KCAP + c) * 8;
            o0 = d[0]; o1 = d[1]; o2 = d[2]; o3 = d[3]; o4 = d[4]; o5 = d[5];
        }
        float* op = out + (size_t)b * 600 + (size_t)t * 6;
        op[0] = o0; op[1] = o1; op[2] = o2; op[3] = o3; op[4] = o4; op[5] = o5;
    }
}

extern "C" void kernel_launch(void* const* d_in, const int* in_sizes, int n_in,
                              void* d_out, int out_size, void* d_ws, size_t ws_size,
                              hipStream_t stream) {
    const float* in = (const float*)d_in[0];
    float* out = (float*)d_out;
    char* ws = (char*)d_ws;
    u32* hist  = (u32*)(ws + OFF_HIST);
    int* vcnt  = (int*)(ws + OFF_VCNT);
    int* Mb    = (int*)(ws + OFF_M);
    u64* vbuf  = (u64*)(ws + OFF_VBUF);
    float* det = (float*)(ws + OFF_DET);
    float4* cor = (float4*)(ws + OFF_COR);
    float* area = (float*)(ws + OFF_AREA);
    u64* mask  = (u64*)(ws + OFF_MASK);

    hipMemsetAsync(ws, 0, MEMSET_BYTES, stream);
    k1_hist  <<<(NB * NANCH) / 256, 256, 0, stream>>>(in, hist, vcnt, vbuf);
    k2345_cut_sort_decode<<<NB, 1024, 0, stream>>>(in, hist, vbuf, vcnt, Mb, det, cor, area);
    k6_mask  <<<NB * 256, 256, 0, stream>>>(cor, area, Mb, mask);
    k78_scan_out<<<NB, 128, 0, stream>>>(mask, Mb, det, out);
}